// Round 5
// baseline (376.642 us; speedup 1.0000x reference)
//
#include <hip/hip_runtime.h>

// ImageRGB_75952201662701 — flip → rotate(bilinear,reflect) → zoom(bilinear,reflect)
// → brightness+clip → contrast(channel-mean)+clip.  [32,512,512,3] f32.
//
// R5: R4's fused rotate+zoom-through-LDS is latency-bound (VALU 29%, Occ 40%,
// HBM 12%) with LDS=31.2KB capping 5 blocks/CU. Shrink tile 64x16 -> 64x8:
// LDS 16.7KB -> 8 blocks/CU (32/32 waves). Trade: avg fill duplication
// 1.14x -> 1.27x. Expect dur 150 -> ~100us via latency hiding.

constexpr int Hh = 512, Ww = 512, Cc = 3, BATCH = 32;
constexpr int HW = Hh * Ww;
constexpr float CTR = 255.5f;                 // (512-1)/2
constexpr size_t IMG_FLOATS = (size_t)HW * Cc;

constexpr int TW = 64, TH = 8;                // output tile per block (256 thr)
constexpr int RW = 99, RH = 14;               // LDS rect capacity (Wr<=97, Hr<=13)

__device__ __forceinline__ int reflect1024(int i) {
    int m = i & 1023;                         // exact for negatives: 2n = 1024 pow2
    return (m < 512) ? m : (1023 - m);
}

__global__ __launch_bounds__(256) void warp_fused(
    const float* __restrict__ in,
    const int* __restrict__ fh, const int* __restrict__ fv,
    const float* __restrict__ angle, const float* __restrict__ zoom,
    const float* __restrict__ delta,
    float* __restrict__ out, double* __restrict__ sums)
{
    __shared__ float lds[RH][RW][3];          // 16632 B
    __shared__ float red[4][3];

    const int b = blockIdx.z;
    const float ang = angle[b];
    const float cs = cosf(ang), sn = sinf(ang);
    const float z  = zoom[b];
    const float dl = delta[b];
    const int fhm = fh[b] ? 511 : 0;          // 511 - x == x ^ 511 for x in [0,511]
    const int fvm = fv[b] ? 511 : 0;
    const float* __restrict__ img  = in  + (size_t)b * IMG_FLOATS;
    float* __restrict__       outb = out + (size_t)b * IMG_FLOATS;

    const int X0 = blockIdx.x * TW;
    const int Y0 = blockIdx.y * TH;

    // pre-reflect integer coord range needed by this tile's zoom taps
    // (z > 0 -> sx monotone in x, so corners bound the range)
    const int rx0 = (int)floorf(z * ((float)X0 - CTR) + CTR);
    const int ry0 = (int)floorf(z * ((float)Y0 - CTR) + CTR);
    const int rx1 = (int)floorf(z * ((float)(X0 + TW - 1) - CTR) + CTR) + 1;
    const int ry1 = (int)floorf(z * ((float)(Y0 + TH - 1) - CTR) + CTR) + 1;
    const int Wr = rx1 - rx0 + 1;             // <= 97 for z <= 1.5
    const int Hr = ry1 - ry0 + 1;             // <= 13
    const int N  = Wr * Hr;

    // ---- fill: rotated-image pixels at reflected coords, into LDS rect ----
    {
        unsigned i  = threadIdx.x;
        unsigned ry = i / (unsigned)Wr;       // one division; then incremental
        unsigned rx = i - ry * (unsigned)Wr;
        const unsigned q = 256u / (unsigned)Wr;
        const unsigned r = 256u - q * (unsigned)Wr;
        while (i < (unsigned)N) {
            const int gx = reflect1024(rx0 + (int)rx);
            const int gy = reflect1024(ry0 + (int)ry);
            const float fx = (float)gx - CTR, fy = (float)gy - CTR;
            // reference: sx = a*x + b*y + cx with a=cos, b=-sin  (IEEE-identical)
            const float sx = cs * fx - sn * fy + CTR;
            const float sy = sn * fx + cs * fy + CTR;
            const float xf = floorf(sx), yf = floorf(sy);
            const float wx = sx - xf, wy = sy - yf;
            const int xa = reflect1024((int)xf)     ^ fhm;
            const int xb = reflect1024((int)xf + 1) ^ fhm;
            const int ya = reflect1024((int)yf)     ^ fvm;
            const int yb = reflect1024((int)yf + 1) ^ fvm;
            const float* p00 = img + (ya * Ww + xa) * Cc;
            const float* p01 = img + (ya * Ww + xb) * Cc;
            const float* p10 = img + (yb * Ww + xa) * Cc;
            const float* p11 = img + (yb * Ww + xb) * Cc;
            const float w1y = 1.f - wy, w1x = 1.f - wx;
            #pragma unroll
            for (int c = 0; c < 3; ++c) {
                lds[ry][rx][c] = ((p00[c] * w1y) * w1x) + ((p01[c] * w1y) * wx)
                               + ((p10[c] * wy) * w1x)  + ((p11[c] * wy) * wx);
            }
            i += 256;
            rx += r; ry += q;
            if (rx >= (unsigned)Wr) { rx -= (unsigned)Wr; ry += 1u; }
        }
    }
    __syncthreads();

    // ---- zoom from LDS + brightness + clip + store + channel sums ----
    const int tx  = threadIdx.x & 63;
    const int ty0 = threadIdx.x >> 6;
    const float sx = z * ((float)(X0 + tx) - CTR) + CTR;
    const float xf = floorf(sx);
    const float wx = sx - xf;
    const int lxa = (int)xf - rx0;            // in [0, Wr-2]
    const float w1x = 1.f - wx;

    float s0 = 0.f, s1 = 0.f, s2 = 0.f;
    #pragma unroll
    for (int k = 0; k < 2; ++k) {
        const int y = Y0 + ty0 + (k << 2);    // wave writes one full 64-px row
        const float sy = z * ((float)y - CTR) + CTR;
        const float yf = floorf(sy);
        const float wy = sy - yf;
        const int lya = (int)yf - ry0;        // in [0, Hr-2]
        const float w1y = 1.f - wy;
        float* o = outb + (size_t)((y << 9) + X0 + tx) * 3;
        #pragma unroll
        for (int c = 0; c < 3; ++c) {
            float t = ((lds[lya][lxa][c] * w1y) * w1x) + ((lds[lya][lxa + 1][c] * w1y) * wx)
                    + ((lds[lya + 1][lxa][c] * wy) * w1x) + ((lds[lya + 1][lxa + 1][c] * wy) * wx);
            t = fminf(fmaxf(t + dl, 0.f), 255.f);     // brightness + clip
            o[c] = t;
            if (c == 0) s0 += t; else if (c == 1) s1 += t; else s2 += t;
        }
    }

    // block reduce -> 3 double atomics (512 blocks/image, 32 distinct b -> light)
    #pragma unroll
    for (int off = 32; off > 0; off >>= 1) {
        s0 += __shfl_down(s0, off);
        s1 += __shfl_down(s1, off);
        s2 += __shfl_down(s2, off);
    }
    const int lane = threadIdx.x & 63, wid = threadIdx.x >> 6;
    if (lane == 0) { red[wid][0] = s0; red[wid][1] = s1; red[wid][2] = s2; }
    __syncthreads();
    if (threadIdx.x == 0) {
        atomicAdd(&sums[b * 3 + 0], (double)red[0][0] + red[1][0] + red[2][0] + red[3][0]);
        atomicAdd(&sums[b * 3 + 1], (double)red[0][1] + red[1][1] + red[2][1] + red[3][1]);
        atomicAdd(&sums[b * 3 + 2], (double)red[0][2] + red[1][2] + red[2][2] + red[3][2]);
    }
}

// ---------- Pass 2: contrast about per-channel mean + clip (4 x float4/thread) ----------
__global__ __launch_bounds__(256) void contrast_pass(
    float* __restrict__ out, const double* __restrict__ sums,
    const float* __restrict__ contrast)
{
    const int b = blockIdx.y;
    const float f = contrast[b];
    const double invN = 1.0 / (double)HW;
    const float m0 = (float)(sums[b * 3 + 0] * invN);
    const float m1 = (float)(sums[b * 3 + 1] * invN);
    const float m2 = (float)(sums[b * 3 + 2] * invN);
    float4* base = reinterpret_cast<float4*>(out + (size_t)b * IMG_FLOATS);

    #pragma unroll
    for (int it = 0; it < 4; ++it) {
        const int i4 = it * 49152 + blockIdx.x * 256 + threadIdx.x;
        float4 v = base[i4];
        int c = (int)(((unsigned)i4 * 4u) % 3u);
        float m;
        m = (c == 0) ? m0 : ((c == 1) ? m1 : m2);
        v.x = fminf(fmaxf((v.x - m) * f + m, 0.f), 255.f); c = (c == 2) ? 0 : c + 1;
        m = (c == 0) ? m0 : ((c == 1) ? m1 : m2);
        v.y = fminf(fmaxf((v.y - m) * f + m, 0.f), 255.f); c = (c == 2) ? 0 : c + 1;
        m = (c == 0) ? m0 : ((c == 1) ? m1 : m2);
        v.z = fminf(fmaxf((v.z - m) * f + m, 0.f), 255.f); c = (c == 2) ? 0 : c + 1;
        m = (c == 0) ? m0 : ((c == 1) ? m1 : m2);
        v.w = fminf(fmaxf((v.w - m) * f + m, 0.f), 255.f);
        base[i4] = v;
    }
}

extern "C" void kernel_launch(void* const* d_in, const int* in_sizes, int n_in,
                              void* d_out, int out_size, void* d_ws, size_t ws_size,
                              hipStream_t stream) {
    const float* in       = (const float*)d_in[0];
    const int*   fh       = (const int*)d_in[1];
    const int*   fv       = (const int*)d_in[2];
    const float* angle    = (const float*)d_in[3];
    const float* zoom     = (const float*)d_in[4];
    const float* delta    = (const float*)d_in[5];
    const float* contrast = (const float*)d_in[6];
    float*  out  = (float*)d_out;
    double* sums = (double*)d_ws;

    // ws re-poisoned to 0xAA each call — zero the sum accumulators.
    hipMemsetAsync(d_ws, 0, BATCH * 3 * sizeof(double), stream);

    dim3 blk(256);
    dim3 g1(Ww / TW, Hh / TH, BATCH);        // 8 x 64 x 32 = 16384 blocks
    warp_fused<<<g1, blk, 0, stream>>>(in, fh, fv, angle, zoom, delta, out, sums);

    dim3 g2(192, BATCH);                     // 4 float4/thread over 96MB
    contrast_pass<<<g2, blk, 0, stream>>>(out, sums, contrast);
}

// Round 6
// 309.398 us; speedup vs baseline: 1.2173x; 1.2173x over previous
//
#include <hip/hip_runtime.h>

// ImageRGB_75952201662701 — flip → rotate(bilinear,reflect) → zoom(bilinear,reflect)
// → brightness+clip → contrast(channel-mean)+clip.  [32,512,512,3] f32.
//
// R6: R4 geometry (64x16 tile, 31.2KB LDS) was best (150us) but issue-bound in
// the fill gather (12 scalar loads/pixel; R5's VGPR=20 codegen showed load
// serialization is the killer). Vectorize taps as float3 (dwordx3, 4 loads/px),
// fixed-trip exec-guarded fill loop (K=10) for cross-iteration load pipelining,
// __launch_bounds__(256,5) to let the allocator keep loads in flight.

constexpr int Hh = 512, Ww = 512, Cc = 3, BATCH = 32;
constexpr int HW = Hh * Ww;
constexpr float CTR = 255.5f;                 // (512-1)/2
constexpr size_t IMG_FLOATS = (size_t)HW * Cc;

constexpr int TW = 64, TH = 16;               // output tile per block (256 thr)
constexpr int RW = 99, RH = 26;               // LDS rect capacity (Wr<=97, Hr<=25)
constexpr int KFILL = 10;                     // ceil(97*25 / 256)

__device__ __forceinline__ int reflect1024(int i) {
    int m = i & 1023;                         // exact for negatives: 2n = 1024 pow2
    return (m < 512) ? m : (1023 - m);
}

__global__ __launch_bounds__(256, 5) void warp_fused(
    const float* __restrict__ in,
    const int* __restrict__ fh, const int* __restrict__ fv,
    const float* __restrict__ angle, const float* __restrict__ zoom,
    const float* __restrict__ delta,
    float* __restrict__ out, double* __restrict__ sums)
{
    __shared__ float3 lds[RH][RW];            // 30888 B
    __shared__ float red[4][3];

    const int b = blockIdx.z;
    const float ang = angle[b];
    const float cs = cosf(ang), sn = sinf(ang);
    const float z  = zoom[b];
    const float dl = delta[b];
    const int fhm = fh[b] ? 511 : 0;          // 511 - x == x ^ 511 for x in [0,511]
    const int fvm = fv[b] ? 511 : 0;
    const float3* __restrict__ img = (const float3*)(in + (size_t)b * IMG_FLOATS);
    float* __restrict__ outb = out + (size_t)b * IMG_FLOATS;

    const int X0 = blockIdx.x * TW;
    const int Y0 = blockIdx.y * TH;

    // pre-reflect integer coord range needed by this tile's zoom taps
    // (z > 0 -> sx monotone in x, so corners bound the range)
    const int rx0 = (int)floorf(z * ((float)X0 - CTR) + CTR);
    const int ry0 = (int)floorf(z * ((float)Y0 - CTR) + CTR);
    const int rx1 = (int)floorf(z * ((float)(X0 + TW - 1) - CTR) + CTR) + 1;
    const int ry1 = (int)floorf(z * ((float)(Y0 + TH - 1) - CTR) + CTR) + 1;
    const unsigned Wr = (unsigned)(rx1 - rx0 + 1);   // <= 97 for z <= 1.5
    const unsigned Hr = (unsigned)(ry1 - ry0 + 1);   // <= 25
    const unsigned N  = Wr * Hr;

    // ---- fill: rotated-image pixels at reflected coords, into LDS rect ----
    {
        unsigned i  = threadIdx.x;
        unsigned ry = i / Wr;                 // one division; then incremental
        unsigned rx = i - ry * Wr;
        const unsigned q = 256u / Wr;
        const unsigned r = 256u - q * Wr;
        #pragma unroll
        for (int t = 0; t < KFILL; ++t) {
            if (i < N) {
                const int gx = reflect1024(rx0 + (int)rx);
                const int gy = reflect1024(ry0 + (int)ry);
                const float fx = (float)gx - CTR, fy = (float)gy - CTR;
                // reference: sx = a*x + b*y + cx with a=cos, b=-sin
                const float sx = cs * fx - sn * fy + CTR;
                const float sy = sn * fx + cs * fy + CTR;
                const float xf = floorf(sx), yf = floorf(sy);
                const float wx = sx - xf, wy = sy - yf;
                const int xa = reflect1024((int)xf)     ^ fhm;
                const int xb = reflect1024((int)xf + 1) ^ fhm;
                const int ya = reflect1024((int)yf)     ^ fvm;
                const int yb = reflect1024((int)yf + 1) ^ fvm;
                const float3 v00 = img[ya * Ww + xa];   // dwordx3 vector taps
                const float3 v01 = img[ya * Ww + xb];
                const float3 v10 = img[yb * Ww + xa];
                const float3 v11 = img[yb * Ww + xb];
                const float w1y = 1.f - wy, w1x = 1.f - wx;
                float3 o;
                o.x = ((v00.x * w1y) * w1x) + ((v01.x * w1y) * wx)
                    + ((v10.x * wy) * w1x)  + ((v11.x * wy) * wx);
                o.y = ((v00.y * w1y) * w1x) + ((v01.y * w1y) * wx)
                    + ((v10.y * wy) * w1x)  + ((v11.y * wy) * wx);
                o.z = ((v00.z * w1y) * w1x) + ((v01.z * w1y) * wx)
                    + ((v10.z * wy) * w1x)  + ((v11.z * wy) * wx);
                lds[ry][rx] = o;
            }
            i += 256u;
            rx += r; ry += q;
            if (rx >= Wr) { rx -= Wr; ry += 1u; }
        }
    }
    __syncthreads();

    // ---- zoom from LDS + brightness + clip + store + channel sums ----
    const int tx  = threadIdx.x & 63;
    const int ty0 = threadIdx.x >> 6;
    const float sx = z * ((float)(X0 + tx) - CTR) + CTR;
    const float xf = floorf(sx);
    const float wx = sx - xf;
    const int lxa = (int)xf - rx0;            // in [0, Wr-2]
    const float w1x = 1.f - wx;

    float s0 = 0.f, s1 = 0.f, s2 = 0.f;
    #pragma unroll
    for (int k = 0; k < 4; ++k) {
        const int y = Y0 + ty0 + (k << 2);    // wave writes one full 64-px row
        const float sy = z * ((float)y - CTR) + CTR;
        const float yf = floorf(sy);
        const float wy = sy - yf;
        const int lya = (int)yf - ry0;        // in [0, Hr-2]
        const float w1y = 1.f - wy;
        const float3 a0 = lds[lya][lxa],     a1 = lds[lya][lxa + 1];
        const float3 b0 = lds[lya + 1][lxa], b1 = lds[lya + 1][lxa + 1];
        float3 t;
        t.x = ((a0.x * w1y) * w1x) + ((a1.x * w1y) * wx)
            + ((b0.x * wy) * w1x)  + ((b1.x * wy) * wx);
        t.y = ((a0.y * w1y) * w1x) + ((a1.y * w1y) * wx)
            + ((b0.y * wy) * w1x)  + ((b1.y * wy) * wx);
        t.z = ((a0.z * w1y) * w1x) + ((a1.z * w1y) * wx)
            + ((b0.z * wy) * w1x)  + ((b1.z * wy) * wx);
        t.x = fminf(fmaxf(t.x + dl, 0.f), 255.f);     // brightness + clip
        t.y = fminf(fmaxf(t.y + dl, 0.f), 255.f);
        t.z = fminf(fmaxf(t.z + dl, 0.f), 255.f);
        *(float3*)(outb + (size_t)((y << 9) + X0 + tx) * 3) = t;
        s0 += t.x; s1 += t.y; s2 += t.z;
    }

    // block reduce -> 3 double atomics (256 blocks/image contend lightly)
    #pragma unroll
    for (int off = 32; off > 0; off >>= 1) {
        s0 += __shfl_down(s0, off);
        s1 += __shfl_down(s1, off);
        s2 += __shfl_down(s2, off);
    }
    const int lane = threadIdx.x & 63, wid = threadIdx.x >> 6;
    if (lane == 0) { red[wid][0] = s0; red[wid][1] = s1; red[wid][2] = s2; }
    __syncthreads();
    if (threadIdx.x == 0) {
        atomicAdd(&sums[b * 3 + 0], (double)red[0][0] + red[1][0] + red[2][0] + red[3][0]);
        atomicAdd(&sums[b * 3 + 1], (double)red[0][1] + red[1][1] + red[2][1] + red[3][1]);
        atomicAdd(&sums[b * 3 + 2], (double)red[0][2] + red[1][2] + red[2][2] + red[3][2]);
    }
}

// ---------- Pass 2: contrast about per-channel mean + clip (4 x float4/thread) ----------
__global__ __launch_bounds__(256) void contrast_pass(
    float* __restrict__ out, const double* __restrict__ sums,
    const float* __restrict__ contrast)
{
    const int b = blockIdx.y;
    const float f = contrast[b];
    const double invN = 1.0 / (double)HW;
    const float m0 = (float)(sums[b * 3 + 0] * invN);
    const float m1 = (float)(sums[b * 3 + 1] * invN);
    const float m2 = (float)(sums[b * 3 + 2] * invN);
    float4* base = reinterpret_cast<float4*>(out + (size_t)b * IMG_FLOATS);

    #pragma unroll
    for (int it = 0; it < 4; ++it) {
        const int i4 = it * 49152 + blockIdx.x * 256 + threadIdx.x;
        float4 v = base[i4];
        int c = (int)(((unsigned)i4 * 4u) % 3u);
        float m;
        m = (c == 0) ? m0 : ((c == 1) ? m1 : m2);
        v.x = fminf(fmaxf((v.x - m) * f + m, 0.f), 255.f); c = (c == 2) ? 0 : c + 1;
        m = (c == 0) ? m0 : ((c == 1) ? m1 : m2);
        v.y = fminf(fmaxf((v.y - m) * f + m, 0.f), 255.f); c = (c == 2) ? 0 : c + 1;
        m = (c == 0) ? m0 : ((c == 1) ? m1 : m2);
        v.z = fminf(fmaxf((v.z - m) * f + m, 0.f), 255.f); c = (c == 2) ? 0 : c + 1;
        m = (c == 0) ? m0 : ((c == 1) ? m1 : m2);
        v.w = fminf(fmaxf((v.w - m) * f + m, 0.f), 255.f);
        base[i4] = v;
    }
}

extern "C" void kernel_launch(void* const* d_in, const int* in_sizes, int n_in,
                              void* d_out, int out_size, void* d_ws, size_t ws_size,
                              hipStream_t stream) {
    const float* in       = (const float*)d_in[0];
    const int*   fh       = (const int*)d_in[1];
    const int*   fv       = (const int*)d_in[2];
    const float* angle    = (const float*)d_in[3];
    const float* zoom     = (const float*)d_in[4];
    const float* delta    = (const float*)d_in[5];
    const float* contrast = (const float*)d_in[6];
    float*  out  = (float*)d_out;
    double* sums = (double*)d_ws;

    // ws re-poisoned to 0xAA each call — zero the sum accumulators.
    hipMemsetAsync(d_ws, 0, BATCH * 3 * sizeof(double), stream);

    dim3 blk(256);
    dim3 g1(Ww / TW, Hh / TH, BATCH);        // 8 x 32 x 32 = 8192 blocks
    warp_fused<<<g1, blk, 0, stream>>>(in, fh, fv, angle, zoom, delta, out, sums);

    dim3 g2(192, BATCH);                     // 4 float4/thread over 96MB
    contrast_pass<<<g2, blk, 0, stream>>>(out, sums, contrast);
}

// Round 7
// 306.079 us; speedup vs baseline: 1.2305x; 1.0108x over previous
//
#include <hip/hip_runtime.h>

// ImageRGB_75952201662701 — flip → rotate(bilinear,reflect) → zoom(bilinear,reflect)
// → brightness+clip → contrast(channel-mean)+clip.  [32,512,512,3] f32.
//
// R7: R4==R6 (149us, VGPR 44 both) proved the compiler never increased fill
// MLP on its own. Explicit 2-deep software pipeline in the fill gather:
// issue pixel t+1's 4 tap loads (named regs) BEFORE consuming pixel t's, so
// ~8 loads stay in flight per thread (counted vmcnt). __launch_bounds__(256,4)
// raises the VGPR cap to 128 (R5: occupancy is not the binding constraint).
// Zoom / reduce / contrast phases byte-identical to the passing R4/R6 code.

constexpr int Hh = 512, Ww = 512, Cc = 3, BATCH = 32;
constexpr int HW = Hh * Ww;
constexpr float CTR = 255.5f;                 // (512-1)/2
constexpr size_t IMG_FLOATS = (size_t)HW * Cc;

constexpr int TW = 64, TH = 16;               // output tile per block (256 thr)
constexpr int RW = 99, RH = 26;               // LDS rect capacity (Wr<=97, Hr<=25)
constexpr int KFILL = 10;                     // ceil(max N / 256) = ceil(2328/256)

__device__ __forceinline__ int reflect1024(int i) {
    int m = i & 1023;                         // exact for negatives: 2n = 1024 pow2
    return (m < 512) ? m : (1023 - m);
}

// compute source taps + weights for rotated-image pixel (RX,RY) and ISSUE loads
#define LOADPX(RX, RY, WX, WY, T00, T01, T10, T11)                              \
    {                                                                           \
        const int gx_ = reflect1024(rx0 + (int)(RX));                           \
        const int gy_ = reflect1024(ry0 + (int)(RY));                           \
        const float fx_ = (float)gx_ - CTR, fy_ = (float)gy_ - CTR;             \
        /* reference: sx = a*x + b*y + cx with a=cos, b=-sin */                 \
        const float sx_ = cs * fx_ - sn * fy_ + CTR;                            \
        const float sy_ = sn * fx_ + cs * fy_ + CTR;                            \
        const float xf_ = floorf(sx_), yf_ = floorf(sy_);                       \
        (WX) = sx_ - xf_; (WY) = sy_ - yf_;                                     \
        const int xa_ = reflect1024((int)xf_)     ^ fhm;                        \
        const int xb_ = reflect1024((int)xf_ + 1) ^ fhm;                        \
        const int ya_ = reflect1024((int)yf_)     ^ fvm;                        \
        const int yb_ = reflect1024((int)yf_ + 1) ^ fvm;                        \
        (T00) = img[ya_ * Ww + xa_]; (T01) = img[ya_ * Ww + xb_];               \
        (T10) = img[yb_ * Ww + xa_]; (T11) = img[yb_ * Ww + xb_];               \
    }

// bilinear combine (reference op order) + LDS store
#define STOREPX(RX, RY, WX, WY, T00, T01, T10, T11)                             \
    {                                                                           \
        const float w1y_ = 1.f - (WY), w1x_ = 1.f - (WX);                       \
        float3 o_;                                                              \
        o_.x = (((T00).x * w1y_) * w1x_) + (((T01).x * w1y_) * (WX))            \
             + (((T10).x * (WY)) * w1x_) + (((T11).x * (WY)) * (WX));           \
        o_.y = (((T00).y * w1y_) * w1x_) + (((T01).y * w1y_) * (WX))            \
             + (((T10).y * (WY)) * w1x_) + (((T11).y * (WY)) * (WX));           \
        o_.z = (((T00).z * w1y_) * w1x_) + (((T01).z * w1y_) * (WX))            \
             + (((T10).z * (WY)) * w1x_) + (((T11).z * (WY)) * (WX));           \
        lds[(RY)][(RX)] = o_;                                                   \
    }

__global__ __launch_bounds__(256, 4) void warp_fused(
    const float* __restrict__ in,
    const int* __restrict__ fh, const int* __restrict__ fv,
    const float* __restrict__ angle, const float* __restrict__ zoom,
    const float* __restrict__ delta,
    float* __restrict__ out, double* __restrict__ sums)
{
    __shared__ float3 lds[RH][RW];            // 30888 B
    __shared__ float red[4][3];

    const int b = blockIdx.z;
    const float ang = angle[b];
    const float cs = cosf(ang), sn = sinf(ang);
    const float z  = zoom[b];
    const float dl = delta[b];
    const int fhm = fh[b] ? 511 : 0;          // 511 - x == x ^ 511 for x in [0,511]
    const int fvm = fv[b] ? 511 : 0;
    const float3* __restrict__ img = (const float3*)(in + (size_t)b * IMG_FLOATS);
    float* __restrict__ outb = out + (size_t)b * IMG_FLOATS;

    const int X0 = blockIdx.x * TW;
    const int Y0 = blockIdx.y * TH;

    // pre-reflect integer coord range needed by this tile's zoom taps
    // (z > 0 -> sx monotone in x, so corners bound the range)
    const int rx0 = (int)floorf(z * ((float)X0 - CTR) + CTR);
    const int ry0 = (int)floorf(z * ((float)Y0 - CTR) + CTR);
    const int rx1 = (int)floorf(z * ((float)(X0 + TW - 1) - CTR) + CTR) + 1;
    const int ry1 = (int)floorf(z * ((float)(Y0 + TH - 1) - CTR) + CTR) + 1;
    const unsigned Wr = (unsigned)(rx1 - rx0 + 1);   // <= 97 for z <= 1.5
    const unsigned Hr = (unsigned)(ry1 - ry0 + 1);   // <= 25
    const unsigned N  = Wr * Hr;

    // ---- fill: 2-deep software-pipelined gather into LDS rect ----
    {
        unsigned i  = threadIdx.x;
        unsigned ry = i / Wr;                 // one division; then incremental
        unsigned rx = i - ry * Wr;
        const unsigned q = 256u / Wr;
        const unsigned r = 256u - q * Wr;

        bool cv = (i < N);                    // current staged pixel valid?
        unsigned crx = rx, cry = ry;
        float cwx, cwy; float3 c00, c01, c10, c11;
        if (cv) LOADPX(crx, cry, cwx, cwy, c00, c01, c10, c11);

        #pragma unroll
        for (int t = 1; t <= KFILL; ++t) {
            i += 256u;
            rx += r; ry += q;
            if (rx >= Wr) { rx -= Wr; ry += 1u; }
            const bool nv = (t < KFILL) && (i < N);
            unsigned nrx = rx, nry = ry;
            float nwx, nwy; float3 n00, n01, n10, n11;
            if (nv) LOADPX(nrx, nry, nwx, nwy, n00, n01, n10, n11);   // issue next loads
            if (cv) STOREPX(crx, cry, cwx, cwy, c00, c01, c10, c11);  // consume current
            cv = nv; crx = nrx; cry = nry; cwx = nwx; cwy = nwy;
            c00 = n00; c01 = n01; c10 = n10; c11 = n11;
        }
    }
    __syncthreads();

    // ---- zoom from LDS + brightness + clip + store + channel sums ----
    const int tx  = threadIdx.x & 63;
    const int ty0 = threadIdx.x >> 6;
    const float sx = z * ((float)(X0 + tx) - CTR) + CTR;
    const float xf = floorf(sx);
    const float wx = sx - xf;
    const int lxa = (int)xf - rx0;            // in [0, Wr-2]
    const float w1x = 1.f - wx;

    float s0 = 0.f, s1 = 0.f, s2 = 0.f;
    #pragma unroll
    for (int k = 0; k < 4; ++k) {
        const int y = Y0 + ty0 + (k << 2);    // wave writes one full 64-px row
        const float sy = z * ((float)y - CTR) + CTR;
        const float yf = floorf(sy);
        const float wy = sy - yf;
        const int lya = (int)yf - ry0;        // in [0, Hr-2]
        const float w1y = 1.f - wy;
        const float3 a0 = lds[lya][lxa],     a1 = lds[lya][lxa + 1];
        const float3 b0 = lds[lya + 1][lxa], b1 = lds[lya + 1][lxa + 1];
        float3 t;
        t.x = ((a0.x * w1y) * w1x) + ((a1.x * w1y) * wx)
            + ((b0.x * wy) * w1x)  + ((b1.x * wy) * wx);
        t.y = ((a0.y * w1y) * w1x) + ((a1.y * w1y) * wx)
            + ((b0.y * wy) * w1x)  + ((b1.y * wy) * wx);
        t.z = ((a0.z * w1y) * w1x) + ((a1.z * w1y) * wx)
            + ((b0.z * wy) * w1x)  + ((b1.z * wy) * wx);
        t.x = fminf(fmaxf(t.x + dl, 0.f), 255.f);     // brightness + clip
        t.y = fminf(fmaxf(t.y + dl, 0.f), 255.f);
        t.z = fminf(fmaxf(t.z + dl, 0.f), 255.f);
        *(float3*)(outb + (size_t)((y << 9) + X0 + tx) * 3) = t;
        s0 += t.x; s1 += t.y; s2 += t.z;
    }

    // block reduce -> 3 double atomics (256 blocks/image contend lightly)
    #pragma unroll
    for (int off = 32; off > 0; off >>= 1) {
        s0 += __shfl_down(s0, off);
        s1 += __shfl_down(s1, off);
        s2 += __shfl_down(s2, off);
    }
    const int lane = threadIdx.x & 63, wid = threadIdx.x >> 6;
    if (lane == 0) { red[wid][0] = s0; red[wid][1] = s1; red[wid][2] = s2; }
    __syncthreads();
    if (threadIdx.x == 0) {
        atomicAdd(&sums[b * 3 + 0], (double)red[0][0] + red[1][0] + red[2][0] + red[3][0]);
        atomicAdd(&sums[b * 3 + 1], (double)red[0][1] + red[1][1] + red[2][1] + red[3][1]);
        atomicAdd(&sums[b * 3 + 2], (double)red[0][2] + red[1][2] + red[2][2] + red[3][2]);
    }
}

// ---------- Pass 2: contrast about per-channel mean + clip (4 x float4/thread) ----------
__global__ __launch_bounds__(256) void contrast_pass(
    float* __restrict__ out, const double* __restrict__ sums,
    const float* __restrict__ contrast)
{
    const int b = blockIdx.y;
    const float f = contrast[b];
    const double invN = 1.0 / (double)HW;
    const float m0 = (float)(sums[b * 3 + 0] * invN);
    const float m1 = (float)(sums[b * 3 + 1] * invN);
    const float m2 = (float)(sums[b * 3 + 2] * invN);
    float4* base = reinterpret_cast<float4*>(out + (size_t)b * IMG_FLOATS);

    #pragma unroll
    for (int it = 0; it < 4; ++it) {
        const int i4 = it * 49152 + blockIdx.x * 256 + threadIdx.x;
        float4 v = base[i4];
        int c = (int)(((unsigned)i4 * 4u) % 3u);
        float m;
        m = (c == 0) ? m0 : ((c == 1) ? m1 : m2);
        v.x = fminf(fmaxf((v.x - m) * f + m, 0.f), 255.f); c = (c == 2) ? 0 : c + 1;
        m = (c == 0) ? m0 : ((c == 1) ? m1 : m2);
        v.y = fminf(fmaxf((v.y - m) * f + m, 0.f), 255.f); c = (c == 2) ? 0 : c + 1;
        m = (c == 0) ? m0 : ((c == 1) ? m1 : m2);
        v.z = fminf(fmaxf((v.z - m) * f + m, 0.f), 255.f); c = (c == 2) ? 0 : c + 1;
        m = (c == 0) ? m0 : ((c == 1) ? m1 : m2);
        v.w = fminf(fmaxf((v.w - m) * f + m, 0.f), 255.f);
        base[i4] = v;
    }
}

extern "C" void kernel_launch(void* const* d_in, const int* in_sizes, int n_in,
                              void* d_out, int out_size, void* d_ws, size_t ws_size,
                              hipStream_t stream) {
    const float* in       = (const float*)d_in[0];
    const int*   fh       = (const int*)d_in[1];
    const int*   fv       = (const int*)d_in[2];
    const float* angle    = (const float*)d_in[3];
    const float* zoom     = (const float*)d_in[4];
    const float* delta    = (const float*)d_in[5];
    const float* contrast = (const float*)d_in[6];
    float*  out  = (float*)d_out;
    double* sums = (double*)d_ws;

    // ws re-poisoned to 0xAA each call — zero the sum accumulators.
    hipMemsetAsync(d_ws, 0, BATCH * 3 * sizeof(double), stream);

    dim3 blk(256);
    dim3 g1(Ww / TW, Hh / TH, BATCH);        // 8 x 32 x 32 = 8192 blocks
    warp_fused<<<g1, blk, 0, stream>>>(in, fh, fv, angle, zoom, delta, out, sums);

    dim3 g2(192, BATCH);                     // 4 float4/thread over 96MB
    contrast_pass<<<g2, blk, 0, stream>>>(out, sums, contrast);
}

// Round 8
// 279.061 us; speedup vs baseline: 1.3497x; 1.0968x over previous
//
#include <hip/hip_runtime.h>

// ImageRGB_75952201662701 — flip → rotate(bilinear,reflect) → zoom(bilinear,reflect)
// → brightness+clip → contrast(channel-mean)+clip.  [32,512,512,3] f32.
//
// R8: R6/R7 proved guarded (branchy) fill loops are codegen no-ops (VGPR stuck
// at 44, loads sunk to uses). This round: BRANCHLESS pair-ILP fill — each
// iteration handles pixels (i, i+256) in straight-line code, tail threads
// clamp to the last valid pixel (same-value duplicate LDS write, benign).
// 8 independent tap loads in flight per thread. Plus angle-adaptive traversal
// (row-major when |sin|<=|cos|, else col-major) so consecutive lanes drift
// <=0.71 px vertically in source space -> fewer cachelines per wave-load.
// Gate: VGPR must move off 44, else experiment void.

constexpr int Hh = 512, Ww = 512, Cc = 3, BATCH = 32;
constexpr int HW = Hh * Ww;
constexpr float CTR = 255.5f;                 // (512-1)/2
constexpr size_t IMG_FLOATS = (size_t)HW * Cc;

constexpr int TW = 64, TH = 16;               // output tile per block (256 thr)
constexpr int RW = 99, RH = 26;               // LDS rect capacity (Wr<=97, Hr<=25)

__device__ __forceinline__ int reflect1024(int i) {
    int m = i & 1023;                         // exact for negatives: 2n = 1024 pow2
    return (m < 512) ? m : (1023 - m);
}

// compute source taps + weights for rotated-image pixel (RX,RY) and ISSUE loads
#define LOADPX(RX, RY, WX, WY, T00, T01, T10, T11)                              \
    {                                                                           \
        const int gx_ = reflect1024(rx0 + (int)(RX));                           \
        const int gy_ = reflect1024(ry0 + (int)(RY));                           \
        const float fx_ = (float)gx_ - CTR, fy_ = (float)gy_ - CTR;             \
        /* reference: sx = a*x + b*y + cx with a=cos, b=-sin */                 \
        const float sx_ = cs * fx_ - sn * fy_ + CTR;                            \
        const float sy_ = sn * fx_ + cs * fy_ + CTR;                            \
        const float xf_ = floorf(sx_), yf_ = floorf(sy_);                       \
        (WX) = sx_ - xf_; (WY) = sy_ - yf_;                                     \
        const int xa_ = reflect1024((int)xf_)     ^ fhm;                        \
        const int xb_ = reflect1024((int)xf_ + 1) ^ fhm;                        \
        const int ya_ = reflect1024((int)yf_)     ^ fvm;                        \
        const int yb_ = reflect1024((int)yf_ + 1) ^ fvm;                        \
        (T00) = img[ya_ * Ww + xa_]; (T01) = img[ya_ * Ww + xb_];               \
        (T10) = img[yb_ * Ww + xa_]; (T11) = img[yb_ * Ww + xb_];               \
    }

// bilinear combine (reference op order) + LDS store
#define STOREPX(RX, RY, WX, WY, T00, T01, T10, T11)                             \
    {                                                                           \
        const float w1y_ = 1.f - (WY), w1x_ = 1.f - (WX);                       \
        float3 o_;                                                              \
        o_.x = (((T00).x * w1y_) * w1x_) + (((T01).x * w1y_) * (WX))            \
             + (((T10).x * (WY)) * w1x_) + (((T11).x * (WY)) * (WX));           \
        o_.y = (((T00).y * w1y_) * w1x_) + (((T01).y * w1y_) * (WX))            \
             + (((T10).y * (WY)) * w1x_) + (((T11).y * (WY)) * (WX));           \
        o_.z = (((T00).z * w1y_) * w1x_) + (((T01).z * w1y_) * (WX))            \
             + (((T10).z * (WY)) * w1x_) + (((T11).z * (WY)) * (WX));           \
        lds[(RY)][(RX)] = o_;                                                   \
    }

__global__ __launch_bounds__(256, 4) void warp_fused(
    const float* __restrict__ in,
    const int* __restrict__ fh, const int* __restrict__ fv,
    const float* __restrict__ angle, const float* __restrict__ zoom,
    const float* __restrict__ delta,
    float* __restrict__ out, double* __restrict__ sums)
{
    __shared__ float3 lds[RH][RW];            // 30888 B
    __shared__ float red[4][3];

    const int b = blockIdx.z;
    const float ang = angle[b];
    const float cs = cosf(ang), sn = sinf(ang);
    const float z  = zoom[b];
    const float dl = delta[b];
    const int fhm = fh[b] ? 511 : 0;          // 511 - x == x ^ 511 for x in [0,511]
    const int fvm = fv[b] ? 511 : 0;
    const float3* __restrict__ img = (const float3*)(in + (size_t)b * IMG_FLOATS);
    float* __restrict__ outb = out + (size_t)b * IMG_FLOATS;

    const int X0 = blockIdx.x * TW;
    const int Y0 = blockIdx.y * TH;

    // pre-reflect integer coord range needed by this tile's zoom taps
    // (z > 0 -> sx monotone in x, so corners bound the range)
    const int rx0 = (int)floorf(z * ((float)X0 - CTR) + CTR);
    const int ry0 = (int)floorf(z * ((float)Y0 - CTR) + CTR);
    const int rx1 = (int)floorf(z * ((float)(X0 + TW - 1) - CTR) + CTR) + 1;
    const int ry1 = (int)floorf(z * ((float)(Y0 + TH - 1) - CTR) + CTR) + 1;
    const unsigned Wr = (unsigned)(rx1 - rx0 + 1);   // <= 97 for z <= 1.5
    const unsigned Hr = (unsigned)(ry1 - ry0 + 1);   // <= 25
    const unsigned N  = Wr * Hr;

    // ---- fill: branchless pair-ILP gather into LDS rect ----
    {
        // fast dim: consecutive lanes step where source drift is smallest.
        // rowmajor (fast=rx): drift/lane = |sn| ; colmajor (fast=ry): |cs|.
        const bool rowmajor = fabsf(sn) <= fabsf(cs);
        const unsigned FW = rowmajor ? Wr : Hr;

        unsigned iA = threadIdx.x;
        unsigned vA = iA / FW;
        unsigned uA = iA - vA * FW;
        const unsigned q1 = 256u / FW, r1 = 256u - q1 * FW;
        const unsigned q2 = 512u / FW, r2 = 512u - q2 * FW;
        const unsigned vL = (N - 1u) / FW;               // last-pixel coords
        const unsigned uL = (N - 1u) - vL * FW;
        const unsigned iters = (N + 511u) >> 9;          // pairs of 256

        for (unsigned t = 0; t < iters; ++t) {
            // pixel B = A + 256 (one wrap correction suffices: r1 < FW)
            unsigned uB = uA + r1, vB = vA + q1;
            const bool wB = (uB >= FW);
            uB = wB ? uB - FW : uB;  vB = wB ? vB + 1u : vB;

            const bool av = (iA < N);
            const bool bv = (iA + 256u < N);
            const unsigned ua = av ? uA : uL, va = av ? vA : vL;
            const unsigned ub = bv ? uB : uL, vb = bv ? vB : vL;
            const unsigned rxa = rowmajor ? ua : va, rya = rowmajor ? va : ua;
            const unsigned rxb = rowmajor ? ub : vb, ryb = rowmajor ? vb : ub;

            // straight line: 8 independent loads issued before any consumer
            float wxa, wya; float3 a00, a01, a10, a11;
            LOADPX(rxa, rya, wxa, wya, a00, a01, a10, a11);
            float wxb, wyb; float3 b00, b01, b10, b11;
            LOADPX(rxb, ryb, wxb, wyb, b00, b01, b10, b11);
            STOREPX(rxa, rya, wxa, wya, a00, a01, a10, a11);
            STOREPX(rxb, ryb, wxb, wyb, b00, b01, b10, b11);

            // advance A by 512 (one wrap correction: r2 < FW)
            iA += 512u;
            unsigned uN = uA + r2, vN = vA + q2;
            const bool wN = (uN >= FW);
            uA = wN ? uN - FW : uN;  vA = wN ? vN + 1u : vN;
        }
    }
    __syncthreads();

    // ---- zoom from LDS + brightness + clip + store + channel sums ----
    const int tx  = threadIdx.x & 63;
    const int ty0 = threadIdx.x >> 6;
    const float sx = z * ((float)(X0 + tx) - CTR) + CTR;
    const float xf = floorf(sx);
    const float wx = sx - xf;
    const int lxa = (int)xf - rx0;            // in [0, Wr-2]
    const float w1x = 1.f - wx;

    float s0 = 0.f, s1 = 0.f, s2 = 0.f;
    #pragma unroll
    for (int k = 0; k < 4; ++k) {
        const int y = Y0 + ty0 + (k << 2);    // wave writes one full 64-px row
        const float sy = z * ((float)y - CTR) + CTR;
        const float yf = floorf(sy);
        const float wy = sy - yf;
        const int lya = (int)yf - ry0;        // in [0, Hr-2]
        const float w1y = 1.f - wy;
        const float3 a0 = lds[lya][lxa],     a1 = lds[lya][lxa + 1];
        const float3 b0 = lds[lya + 1][lxa], b1 = lds[lya + 1][lxa + 1];
        float3 t;
        t.x = ((a0.x * w1y) * w1x) + ((a1.x * w1y) * wx)
            + ((b0.x * wy) * w1x)  + ((b1.x * wy) * wx);
        t.y = ((a0.y * w1y) * w1x) + ((a1.y * w1y) * wx)
            + ((b0.y * wy) * w1x)  + ((b1.y * wy) * wx);
        t.z = ((a0.z * w1y) * w1x) + ((a1.z * w1y) * wx)
            + ((b0.z * wy) * w1x)  + ((b1.z * wy) * wx);
        t.x = fminf(fmaxf(t.x + dl, 0.f), 255.f);     // brightness + clip
        t.y = fminf(fmaxf(t.y + dl, 0.f), 255.f);
        t.z = fminf(fmaxf(t.z + dl, 0.f), 255.f);
        *(float3*)(outb + (size_t)((y << 9) + X0 + tx) * 3) = t;
        s0 += t.x; s1 += t.y; s2 += t.z;
    }

    // block reduce -> 3 double atomics (256 blocks/image contend lightly)
    #pragma unroll
    for (int off = 32; off > 0; off >>= 1) {
        s0 += __shfl_down(s0, off);
        s1 += __shfl_down(s1, off);
        s2 += __shfl_down(s2, off);
    }
    const int lane = threadIdx.x & 63, wid = threadIdx.x >> 6;
    if (lane == 0) { red[wid][0] = s0; red[wid][1] = s1; red[wid][2] = s2; }
    __syncthreads();
    if (threadIdx.x == 0) {
        atomicAdd(&sums[b * 3 + 0], (double)red[0][0] + red[1][0] + red[2][0] + red[3][0]);
        atomicAdd(&sums[b * 3 + 1], (double)red[0][1] + red[1][1] + red[2][1] + red[3][1]);
        atomicAdd(&sums[b * 3 + 2], (double)red[0][2] + red[1][2] + red[2][2] + red[3][2]);
    }
}

// ---------- Pass 2: contrast about per-channel mean + clip (4 x float4/thread) ----------
__global__ __launch_bounds__(256) void contrast_pass(
    float* __restrict__ out, const double* __restrict__ sums,
    const float* __restrict__ contrast)
{
    const int b = blockIdx.y;
    const float f = contrast[b];
    const double invN = 1.0 / (double)HW;
    const float m0 = (float)(sums[b * 3 + 0] * invN);
    const float m1 = (float)(sums[b * 3 + 1] * invN);
    const float m2 = (float)(sums[b * 3 + 2] * invN);
    float4* base = reinterpret_cast<float4*>(out + (size_t)b * IMG_FLOATS);

    #pragma unroll
    for (int it = 0; it < 4; ++it) {
        const int i4 = it * 49152 + blockIdx.x * 256 + threadIdx.x;
        float4 v = base[i4];
        int c = (int)(((unsigned)i4 * 4u) % 3u);
        float m;
        m = (c == 0) ? m0 : ((c == 1) ? m1 : m2);
        v.x = fminf(fmaxf((v.x - m) * f + m, 0.f), 255.f); c = (c == 2) ? 0 : c + 1;
        m = (c == 0) ? m0 : ((c == 1) ? m1 : m2);
        v.y = fminf(fmaxf((v.y - m) * f + m, 0.f), 255.f); c = (c == 2) ? 0 : c + 1;
        m = (c == 0) ? m0 : ((c == 1) ? m1 : m2);
        v.z = fminf(fmaxf((v.z - m) * f + m, 0.f), 255.f); c = (c == 2) ? 0 : c + 1;
        m = (c == 0) ? m0 : ((c == 1) ? m1 : m2);
        v.w = fminf(fmaxf((v.w - m) * f + m, 0.f), 255.f);
        base[i4] = v;
    }
}

extern "C" void kernel_launch(void* const* d_in, const int* in_sizes, int n_in,
                              void* d_out, int out_size, void* d_ws, size_t ws_size,
                              hipStream_t stream) {
    const float* in       = (const float*)d_in[0];
    const int*   fh       = (const int*)d_in[1];
    const int*   fv       = (const int*)d_in[2];
    const float* angle    = (const float*)d_in[3];
    const float* zoom     = (const float*)d_in[4];
    const float* delta    = (const float*)d_in[5];
    const float* contrast = (const float*)d_in[6];
    float*  out  = (float*)d_out;
    double* sums = (double*)d_ws;

    // ws re-poisoned to 0xAA each call — zero the sum accumulators.
    hipMemsetAsync(d_ws, 0, BATCH * 3 * sizeof(double), stream);

    dim3 blk(256);
    dim3 g1(Ww / TW, Hh / TH, BATCH);        // 8 x 32 x 32 = 8192 blocks
    warp_fused<<<g1, blk, 0, stream>>>(in, fh, fv, angle, zoom, delta, out, sums);

    dim3 g2(192, BATCH);                     // 4 float4/thread over 96MB
    contrast_pass<<<g2, blk, 0, stream>>>(out, sums, contrast);
}